// Round 4
// baseline (582.838 us; speedup 1.0000x reference)
//
#include <hip/hip_runtime.h>
#include <math.h>

#define D_DIM 1024     // hidden dim (K)
#define N_EXP 64       // experts (N)
#define BLK_ROWS 64    // rows per block
#define STRIDE 68      // LDS dword stride per row (64 + 4 pad, 16B-aligned)
#define KC 16          // k-columns per quarter per iteration
#define NC 16          // iterations (4 quarters * NC * KC = 1024 = D_DIM)
#define BSX (BLK_ROWS * STRIDE)
#define BSW (N_EXP * STRIDE)

// Mapping: 256 threads = 4 waves (2 row-halves x 2 expert-halves of the 64x64 block tile).
//   lane bits: i = lane&3 (row-lane), j = (lane>>2)&3 (expert-lane), q = lane>>4 (K-quarter)
//   lane tile: 8 rows {wave_r*32 + rr*4 + i} x 8 experts {wave_c*32 + ee*4 + j}, K-quarter q.
// Interleaved i/j keeps every ds_read_b128 at 16 addrs / 4-way broadcast / 2-per-bank (free).
// Inner loop is k-outer: consecutive fmas on the same accumulator are 64 instrs apart,
// so the 4-cyc fma dep latency is fully hidden even at 1 wave/SIMD.

__device__ __forceinline__ void top2_merge(float& m1, float& m2, float o1, float o2) {
    const float lo = fminf(m1, o1);
    m1 = fmaxf(m1, o1);
    m2 = fmaxf(lo, fmaxf(m2, o2));
}

__global__ __launch_bounds__(256, 2)
void spiking_router_kernel(const float* __restrict__ x,
                           const float* __restrict__ Wt,
                           const float* __restrict__ bias,
                           float* __restrict__ out,
                           int m_rows)
{
    __shared__ __align__(16) float xs[2][BSX];
    __shared__ __align__(16) float ws[2][BSW];
    __shared__ float b_s[N_EXP];
    __shared__ float2 tops[BLK_ROWS][2];   // per-row (m1,m2) per expert-half

    const int tid  = threadIdx.x;
    const int blk  = blockIdx.x;
    // staging mapping: thread owns one 64B piece (row sr, K-quarter sq)
    const int sr   = tid >> 2;   // 0..63 : x-row / W-expert index
    const int sq   = tid & 3;    // 0..3  : K-quarter
    // compute mapping
    const int lane   = tid & 63;
    const int wv     = tid >> 6;
    const int i      = lane & 3;         // row-lane
    const int j      = (lane >> 2) & 3;  // expert-lane
    const int q      = lane >> 4;        // K-quarter
    const int wave_r = wv >> 1;          // row half (32 rows)
    const int wave_c = wv & 1;           // expert half (32 experts)

    if (tid < N_EXP) b_s[tid] = bias[tid];

    const long row0 = (long)blk * BLK_ROWS;
    const float* gx = x  + (row0 + sr) * D_DIM + sq * 256;
    const float* gw = Wt + (long)sr   * D_DIM + sq * 256;

    float4 px0, px1, px2, px3, pw0, pw1, pw2, pw3;

    // ---- prologue: load chunk 0 into buffer 0 ----
    {
        const float4* a = (const float4*)gx;
        px0 = a[0]; px1 = a[1]; px2 = a[2]; px3 = a[3];
        const float4* c = (const float4*)gw;
        pw0 = c[0]; pw1 = c[1]; pw2 = c[2]; pw3 = c[3];
    }
    {
        float4* dx = (float4*)&xs[0][sr * STRIDE + sq * KC];
        dx[0] = px0; dx[1] = px1; dx[2] = px2; dx[3] = px3;
        float4* dw = (float4*)&ws[0][sr * STRIDE + sq * KC];
        dw[0] = pw0; dw[1] = pw1; dw[2] = pw2; dw[3] = pw3;
    }

    float acc[64];
    #pragma unroll
    for (int t = 0; t < 64; ++t) acc[t] = 0.0f;

    // per-row / per-expert LDS dword offsets within a buffer
    int xoff[8], woff[8];
    #pragma unroll
    for (int rr = 0; rr < 8; ++rr) xoff[rr] = (wave_r * 32 + rr * 4 + i) * STRIDE + q * KC;
    #pragma unroll
    for (int ee = 0; ee < 8; ++ee) woff[ee] = (wave_c * 32 + ee * 4 + j) * STRIDE + q * KC;

    // ---- main loop: one barrier/iter, LDS double-buffered, reg prefetch ----
    for (int c = 0; c < NC; ++c) {
        __syncthreads();
        const bool more = (c + 1 < NC);
        if (more) {
            const float4* a = (const float4*)(gx + (c + 1) * KC);
            px0 = a[0]; px1 = a[1]; px2 = a[2]; px3 = a[3];
            const float4* w = (const float4*)(gw + (c + 1) * KC);
            pw0 = w[0]; pw1 = w[1]; pw2 = w[2]; pw3 = w[3];
        }
        const float* xb = xs[c & 1];
        const float* wb = ws[c & 1];
        #pragma unroll
        for (int c4 = 0; c4 < 4; ++c4) {
            float4 a[8], w[8];
            #pragma unroll
            for (int rr = 0; rr < 8; ++rr)
                a[rr] = *(const float4*)&xb[xoff[rr] + c4 * 4];
            #pragma unroll
            for (int ee = 0; ee < 8; ++ee)
                w[ee] = *(const float4*)&wb[woff[ee] + c4 * 4];
            // k-outer: same-acc fmas are 64 apart -> no dep-latency stalls
            #pragma unroll
            for (int k = 0; k < 4; ++k) {
                #pragma unroll
                for (int ee = 0; ee < 8; ++ee) {
                    const float wk = (k == 0) ? w[ee].x : (k == 1) ? w[ee].y
                                   : (k == 2) ? w[ee].z : w[ee].w;
                    #pragma unroll
                    for (int rr = 0; rr < 8; ++rr) {
                        const float ak = (k == 0) ? a[rr].x : (k == 1) ? a[rr].y
                                       : (k == 2) ? a[rr].z : a[rr].w;
                        acc[rr * 8 + ee] = fmaf(ak, wk, acc[rr * 8 + ee]);
                    }
                }
            }
        }
        if (more) {
            const int nb = (c + 1) & 1;
            float4* dx = (float4*)&xs[nb][sr * STRIDE + sq * KC];
            dx[0] = px0; dx[1] = px1; dx[2] = px2; dx[3] = px3;
            float4* dw = (float4*)&ws[nb][sr * STRIDE + sq * KC];
            dw[0] = pw0; dw[1] = pw1; dw[2] = pw2; dw[3] = pw3;
        }
    }

    // ---- K-quarter all-reduce (lanes l, l^16, l^32, l^48 share a tile) ----
    #pragma unroll
    for (int t = 0; t < 64; ++t) {
        float v = acc[t];
        v += __shfl_xor(v, 16, 64);
        v += __shfl_xor(v, 32, 64);
        acc[t] = v;
    }
    // bias (after K-sum, before top-2)
    #pragma unroll
    for (int ee = 0; ee < 8; ++ee) {
        const float be = b_s[wave_c * 32 + ee * 4 + j];
        #pragma unroll
        for (int rr = 0; rr < 8; ++rr) acc[rr * 8 + ee] += be;
    }

    // ---- per-row local top-2 over this lane's 8 experts (branchless med3) ----
    float t1[8], t2[8];
    #pragma unroll
    for (int rr = 0; rr < 8; ++rr) {
        float m1 = -INFINITY, m2 = -INFINITY;
        #pragma unroll
        for (int ee = 0; ee < 8; ++ee) {
            const float v = acc[rr * 8 + ee];
            m2 = __builtin_amdgcn_fmed3f(m2, v, m1);
            m1 = fmaxf(m1, v);
        }
        t1[rr] = m1; t2[rr] = m2;
    }
    // merge across the 4 expert-lanes (lane^4, lane^8)
    #pragma unroll
    for (int rr = 0; rr < 8; ++rr) {
        float o1 = __shfl_xor(t1[rr], 4, 64);
        float o2 = __shfl_xor(t2[rr], 4, 64);
        top2_merge(t1[rr], t2[rr], o1, o2);
        o1 = __shfl_xor(t1[rr], 8, 64);
        o2 = __shfl_xor(t2[rr], 8, 64);
        top2_merge(t1[rr], t2[rr], o1, o2);
    }
    // ---- cross-half exchange: global top-2 of the union of the two halves ----
    if (q == 0 && j == 0) {
        #pragma unroll
        for (int rr = 0; rr < 8; ++rr)
            tops[wave_r * 32 + rr * 4 + i][wave_c] = make_float2(t1[rr], t2[rr]);
    }
    __syncthreads();
    float thr[8];
    #pragma unroll
    for (int rr = 0; rr < 8; ++rr) {
        const float2 o = tops[wave_r * 32 + rr * 4 + i][wave_c ^ 1];
        float m1 = t1[rr], m2 = t2[rr];
        top2_merge(m1, m2, o.x, o.y);
        thr[rr] = m2;   // second max of union = top-2 membership threshold
    }

    // ---- quantize + store (step == 1.0): rw = in_top2 ? min(floor(max(v,0)),4) : 0
    float* const olg = out + (long)m_rows * N_EXP;
    const int ecol = wave_c * 32 + j;
    #define STORE_ROW(RR) { \
        const long row = row0 + wave_r * 32 + (RR) * 4 + i; \
        const float th = thr[(RR)]; \
        float* po = out + row * N_EXP + ecol; \
        float* pl = olg + row * N_EXP + ecol; \
        _Pragma("unroll") \
        for (int ee = 0; ee < 8; ++ee) { \
            const float v  = acc[(RR) * 8 + ee]; \
            const float rw = (v >= th) ? fminf(floorf(fmaxf(v, 0.0f)), 4.0f) : 0.0f; \
            po[ee * 4] = rw; \
            pl[ee * 4] = v; \
        } }
    if (q == 0)      { STORE_ROW(0) STORE_ROW(1) }
    else if (q == 1) { STORE_ROW(2) STORE_ROW(3) }
    else if (q == 2) { STORE_ROW(4) STORE_ROW(5) }
    else             { STORE_ROW(6) STORE_ROW(7) }
    #undef STORE_ROW
}

extern "C" void kernel_launch(void* const* d_in, const int* in_sizes, int n_in,
                              void* d_out, int out_size, void* d_ws, size_t ws_size,
                              hipStream_t stream)
{
    const float* x  = (const float*)d_in[0];
    const float* Wt = (const float*)d_in[1];
    const float* b  = (const float*)d_in[2];
    float* out = (float*)d_out;
    const int m_rows = in_sizes[0] / D_DIM;   // 8*4096 = 32768
    const int grid = m_rows / BLK_ROWS;       // 512
    spiking_router_kernel<<<grid, 256, 0, stream>>>(x, Wt, b, out, m_rows);
}

// Round 11
// 518.221 us; speedup vs baseline: 1.1247x; 1.1247x over previous
//
#include <hip/hip_runtime.h>
#include <math.h>

#define D_DIM 1024     // hidden dim (K)
#define N_EXP 64       // experts (N)
#define BLK_ROWS 64    // rows per block
#define STRIDE 68      // LDS dword stride per row (64 + 4 pad, 16B-aligned)
#define KC 16          // k-columns per quarter per iteration
#define NC 16          // iterations (4 quarters * NC * KC = 1024 = D_DIM)
#define BSX (BLK_ROWS * STRIDE)
#define BSW (N_EXP * STRIDE)

// Mapping: 256 threads = 4 waves (2 row-halves x 2 expert-halves of the 64x64 block tile).
//   lane bits: i = lane&3 (row-lane), j = (lane>>2)&3 (expert-lane), q = lane>>4 (K-quarter)
//   lane tile: 8 rows {wave_r*32 + rr*4 + i} x 8 experts {wave_c*32 + ee*4 + j}, K-quarter q.
// Interleaved i/j keeps every ds_read_b128 at 16 addrs / 4-way broadcast / 2-per-bank.
// Measured (round 4): SQ_LDS_BANK_CONFLICT == exactly 1 cyc per b128 read -> ~3 cyc/read,
// LDS pipe ~1.5k cyc/CU-iter << 4096 VALU cyc/SIMD-iter -> GEMM is VALU-bound as designed.
// Epilogue re-layouts through LDS so ALL global stores are float4, block-contiguous.
// (Round-4 lesson: scalar stride-4 stores caused 64x write amplification, 1.07 GB writes,
//  455 us total; this epilogue is the fix.)

__device__ __forceinline__ void top2_merge(float& m1, float& m2, float o1, float o2) {
    const float lo = fminf(m1, o1);
    m1 = fmaxf(m1, o1);
    m2 = fmaxf(lo, fmaxf(m2, o2));
}

__global__ __launch_bounds__(256, 2)
void spiking_router_kernel(const float* __restrict__ x,
                           const float* __restrict__ Wt,
                           const float* __restrict__ bias,
                           float* __restrict__ out,
                           int m_rows)
{
    __shared__ __align__(16) float xs[2][BSX];   // x tiles; xs[0] reused as logit tile in epilogue
    __shared__ __align__(16) float ws[2][BSW];
    __shared__ float b_s[N_EXP];
    __shared__ float2 tops[BLK_ROWS][2];   // per-row (m1,m2) per expert-half

    const int tid  = threadIdx.x;
    const int blk  = blockIdx.x;
    // staging mapping: thread owns one 64B piece (row sr, K-quarter sq)
    const int sr   = tid >> 2;   // 0..63 : x-row / W-expert index
    const int sq   = tid & 3;    // 0..3  : K-quarter
    // compute mapping
    const int lane   = tid & 63;
    const int wv     = tid >> 6;
    const int i      = lane & 3;         // row-lane
    const int j      = (lane >> 2) & 3;  // expert-lane
    const int q      = lane >> 4;        // K-quarter
    const int wave_r = wv >> 1;          // row half (32 rows)
    const int wave_c = wv & 1;           // expert half (32 experts)

    if (tid < N_EXP) b_s[tid] = bias[tid];

    const long row0 = (long)blk * BLK_ROWS;
    const float* gx = x  + (row0 + sr) * D_DIM + sq * 256;
    const float* gw = Wt + (long)sr   * D_DIM + sq * 256;

    float4 px0, px1, px2, px3, pw0, pw1, pw2, pw3;

    // ---- prologue: load chunk 0 into buffer 0 ----
    {
        const float4* a = (const float4*)gx;
        px0 = a[0]; px1 = a[1]; px2 = a[2]; px3 = a[3];
        const float4* c = (const float4*)gw;
        pw0 = c[0]; pw1 = c[1]; pw2 = c[2]; pw3 = c[3];
    }
    {
        float4* dx = (float4*)&xs[0][sr * STRIDE + sq * KC];
        dx[0] = px0; dx[1] = px1; dx[2] = px2; dx[3] = px3;
        float4* dw = (float4*)&ws[0][sr * STRIDE + sq * KC];
        dw[0] = pw0; dw[1] = pw1; dw[2] = pw2; dw[3] = pw3;
    }

    float acc[64];
    #pragma unroll
    for (int t = 0; t < 64; ++t) acc[t] = 0.0f;

    // per-row / per-expert LDS dword offsets within a buffer
    int xoff[8], woff[8];
    #pragma unroll
    for (int rr = 0; rr < 8; ++rr) xoff[rr] = (wave_r * 32 + rr * 4 + i) * STRIDE + q * KC;
    #pragma unroll
    for (int ee = 0; ee < 8; ++ee) woff[ee] = (wave_c * 32 + ee * 4 + j) * STRIDE + q * KC;

    // ---- main loop: one barrier/iter, LDS double-buffered, reg prefetch ----
    for (int c = 0; c < NC; ++c) {
        __syncthreads();
        const bool more = (c + 1 < NC);
        if (more) {
            const float4* a = (const float4*)(gx + (c + 1) * KC);
            px0 = a[0]; px1 = a[1]; px2 = a[2]; px3 = a[3];
            const float4* w = (const float4*)(gw + (c + 1) * KC);
            pw0 = w[0]; pw1 = w[1]; pw2 = w[2]; pw3 = w[3];
        }
        const float* xb = xs[c & 1];
        const float* wb = ws[c & 1];
        #pragma unroll
        for (int c4 = 0; c4 < 4; ++c4) {
            float4 a[8], w[8];
            #pragma unroll
            for (int rr = 0; rr < 8; ++rr)
                a[rr] = *(const float4*)&xb[xoff[rr] + c4 * 4];
            #pragma unroll
            for (int ee = 0; ee < 8; ++ee)
                w[ee] = *(const float4*)&wb[woff[ee] + c4 * 4];
            // k-outer: same-acc fmas are 64 apart -> no dep-latency stalls
            #pragma unroll
            for (int k = 0; k < 4; ++k) {
                #pragma unroll
                for (int ee = 0; ee < 8; ++ee) {
                    const float wk = (k == 0) ? w[ee].x : (k == 1) ? w[ee].y
                                   : (k == 2) ? w[ee].z : w[ee].w;
                    #pragma unroll
                    for (int rr = 0; rr < 8; ++rr) {
                        const float ak = (k == 0) ? a[rr].x : (k == 1) ? a[rr].y
                                       : (k == 2) ? a[rr].z : a[rr].w;
                        acc[rr * 8 + ee] = fmaf(ak, wk, acc[rr * 8 + ee]);
                    }
                }
            }
        }
        if (more) {
            const int nb = (c + 1) & 1;
            float4* dx = (float4*)&xs[nb][sr * STRIDE + sq * KC];
            dx[0] = px0; dx[1] = px1; dx[2] = px2; dx[3] = px3;
            float4* dw = (float4*)&ws[nb][sr * STRIDE + sq * KC];
            dw[0] = pw0; dw[1] = pw1; dw[2] = pw2; dw[3] = pw3;
        }
    }

    // ---- K-quarter all-reduce (lanes l, l^16, l^32, l^48 share a tile) + bias ----
    #pragma unroll
    for (int t = 0; t < 64; ++t) {
        float v = acc[t];
        v += __shfl_xor(v, 16, 64);
        v += __shfl_xor(v, 32, 64);
        acc[t] = v;
    }
    #pragma unroll
    for (int ee = 0; ee < 8; ++ee) {
        const float be = b_s[wave_c * 32 + ee * 4 + j];
        #pragma unroll
        for (int rr = 0; rr < 8; ++rr) acc[rr * 8 + ee] += be;
    }

    // ---- per-row local top-2 over this lane's 8 experts (branchless med3) ----
    float t1[8], t2[8];
    #pragma unroll
    for (int rr = 0; rr < 8; ++rr) {
        float m1 = -INFINITY, m2 = -INFINITY;
        #pragma unroll
        for (int ee = 0; ee < 8; ++ee) {
            const float v = acc[rr * 8 + ee];
            m2 = __builtin_amdgcn_fmed3f(m2, v, m1);
            m1 = fmaxf(m1, v);
        }
        t1[rr] = m1; t2[rr] = m2;
    }
    // merge across the 4 expert-lanes (lane^4, lane^8); result uniform over j and q
    #pragma unroll
    for (int rr = 0; rr < 8; ++rr) {
        float o1 = __shfl_xor(t1[rr], 4, 64);
        float o2 = __shfl_xor(t2[rr], 4, 64);
        top2_merge(t1[rr], t2[rr], o1, o2);
        o1 = __shfl_xor(t1[rr], 8, 64);
        o2 = __shfl_xor(t2[rr], 8, 64);
        top2_merge(t1[rr], t2[rr], o1, o2);
    }

    // ---- epilogue stage 1: scatter logits into LDS tile (xs[0] is free: last loop
    // iteration reads only xs[1], and every wave passed the c=15 barrier) ----
    float* const lg_tile = &xs[0][0];   // [BLK_ROWS][STRIDE]
    if (q == 0) {
        #pragma unroll
        for (int rr = 0; rr < 8; ++rr) {
            const int row = wave_r * 32 + rr * 4 + i;
            #pragma unroll
            for (int ee = 0; ee < 8; ++ee)   // banks 4i+j: conflict-free
                lg_tile[row * STRIDE + wave_c * 32 + ee * 4 + j] = acc[rr * 8 + ee];
        }
        if (j == 0) {
            #pragma unroll
            for (int rr = 0; rr < 8; ++rr)
                tops[wave_r * 32 + rr * 4 + i][wave_c] = make_float2(t1[rr], t2[rr]);
        }
    }
    __syncthreads();

    // ---- epilogue stage 2: coalesced readout + quantize + float4 stores ----
    // thread tid -> row sr (=tid>>2), 16-float chunk sq (=tid&3): block writes are
    // 16 KB contiguous per output (address = base + tid*64B).
    const float2 ta = tops[sr][0];
    const float2 tb = tops[sr][1];
    float u1 = ta.x, u2 = ta.y;
    top2_merge(u1, u2, tb.x, tb.y);
    const float th = u2;                 // 2nd max of union = top-2 membership threshold

    const long row = row0 + sr;
    float* po = out + row * N_EXP + sq * 16;
    float* pl = out + (long)m_rows * N_EXP + row * N_EXP + sq * 16;
    #pragma unroll
    for (int k = 0; k < 4; ++k) {
        const float4 lg = *(const float4*)&lg_tile[sr * STRIDE + sq * 16 + k * 4];
        float4 rw;
        rw.x = (lg.x >= th) ? fminf(floorf(fmaxf(lg.x, 0.0f)), 4.0f) : 0.0f;
        rw.y = (lg.y >= th) ? fminf(floorf(fmaxf(lg.y, 0.0f)), 4.0f) : 0.0f;
        rw.z = (lg.z >= th) ? fminf(floorf(fmaxf(lg.z, 0.0f)), 4.0f) : 0.0f;
        rw.w = (lg.w >= th) ? fminf(floorf(fmaxf(lg.w, 0.0f)), 4.0f) : 0.0f;
        ((float4*)po)[k] = rw;
        ((float4*)pl)[k] = lg;
    }
}

extern "C" void kernel_launch(void* const* d_in, const int* in_sizes, int n_in,
                              void* d_out, int out_size, void* d_ws, size_t ws_size,
                              hipStream_t stream)
{
    const float* x  = (const float*)d_in[0];
    const float* Wt = (const float*)d_in[1];
    const float* b  = (const float*)d_in[2];
    float* out = (float*)d_out;
    const int m_rows = in_sizes[0] / D_DIM;   // 8*4096 = 32768
    const int grid = m_rows / BLK_ROWS;       // 512
    spiking_router_kernel<<<grid, 256, 0, stream>>>(x, Wt, b, out, m_rows);
}